// Round 1
// baseline (744.224 us; speedup 1.0000x reference)
//
#include <hip/hip_runtime.h>
#include <stdint.h>

// ---- types ----
typedef __attribute__((ext_vector_type(4))) float f32x4;
typedef __attribute__((ext_vector_type(8))) short s16x8;
typedef __attribute__((ext_vector_type(4))) short s16x4;
typedef __attribute__((ext_vector_type(4))) unsigned int u32x4;

#define MFMA16(a, b, c) __builtin_amdgcn_mfma_f32_16x16x32_bf16((a), (b), (c), 0, 0, 0)

// B=2, T=8192, D=256; rows = B*T = 16384 flat.

__device__ __forceinline__ unsigned short f2bf(float f) {
  unsigned int u = __float_as_uint(f);
  u += 0x7FFFu + ((u >> 16) & 1u);  // RNE
  return (unsigned short)(u >> 16);
}
__device__ __forceinline__ float bf2f(unsigned short h) {
  return __uint_as_float(((unsigned int)h) << 16);
}

// ---------------- kernel 1: weight transpose + hi/lo split ----------------
// wt layout (shorts): [WqhT 65536][WqlT][WkhT][WklT][WvhT][WvlT], each [n][d].
__global__ void wtrans_kernel(const float* __restrict__ Wq,
                              const float* __restrict__ Wk,
                              const float* __restrict__ Wv,
                              short* __restrict__ wt) {
  int idx = blockIdx.x * 256 + threadIdx.x;   // 768 blocks * 256
  int w = idx >> 16;
  int rc = idx & 65535;
  int d = rc >> 8;
  int n = rc & 255;
  const float* Ws = (w == 0) ? Wq : ((w == 1) ? Wk : Wv);
  float v = Ws[rc];                           // W[d][n], coalesced read
  unsigned short hi = f2bf(v);
  unsigned short lo = f2bf(v - bf2f(hi));
  short* th = wt + w * 131072;
  th[n * 256 + d] = (short)hi;                // WT_h[n][d]
  th[65536 + n * 256 + d] = (short)lo;        // WT_l[n][d]
}

// ---------------- kernel 2: QKV projection (3-term bf16 MFMA) ----------------
// Outputs: Qh/Ql/Kh/Kl [16384][256] bf16 row-major; Vt [2][256][8192] bf16.
__global__ __launch_bounds__(256, 2)
void qkv_kernel(const float* __restrict__ x,
                const float* __restrict__ bq,
                const float* __restrict__ bk,
                const float* __restrict__ bv,
                const short* __restrict__ wt,
                short* __restrict__ Qh, short* __restrict__ Ql,
                short* __restrict__ Kh, short* __restrict__ Kl,
                short* __restrict__ Vt) {
  // X tile 32 rows x 256 cols, hi at [r*264+c], lo at +8448 (stride 264: odd 16B-granule)
  __shared__ short X[16896];
  int tid = threadIdx.x;
  int r0 = blockIdx.x * 32;          // global row base (512 blocks)
  int bidx = r0 >> 13;               // batch
  int tl0 = r0 & 8191;               // t within batch
  // stage + split x
#pragma unroll
  for (int i = 0; i < 8; i++) {
    int E = i * 1024 + tid * 4;
    int r = E >> 8, col = E & 255;
    f32x4 v = *(const f32x4*)(x + (size_t)(r0 + r) * 256 + col);
    s16x4 h, lo;
#pragma unroll
    for (int j = 0; j < 4; j++) {
      unsigned short hh = f2bf(v[j]);
      h[j] = (short)hh;
      lo[j] = (short)f2bf(v[j] - bf2f(hh));
    }
    *(s16x4*)&X[r * 264 + col] = h;
    *(s16x4*)&X[8448 + r * 264 + col] = lo;
  }
  __syncthreads();

  int lane = tid & 63, wv = tid >> 6;
  int quad = lane >> 4, lq = lane & 15;

  // ---- q (waves 0,1) / k (waves 2,3): strip of 16 rows, 16 n-tiles, K=256
  {
    int strip = wv & 1;
    const short* WhT = wt + ((wv < 2) ? 0 : 131072);
    const short* WlT = WhT + 65536;
    f32x4 acc[16];
#pragma unroll
    for (int nt = 0; nt < 16; nt++) acc[nt] = (f32x4){0.f, 0.f, 0.f, 0.f};
    int arow = (strip * 16 + lq) * 264 + quad * 8;
#pragma unroll
    for (int c = 0; c < 8; c++) {
      s16x8 xh = *(const s16x8*)&X[arow + c * 32];
      s16x8 xl = *(const s16x8*)&X[8448 + arow + c * 32];
#pragma unroll
      for (int nt = 0; nt < 16; nt++) {
        int boff = (nt * 16 + lq) * 256 + c * 32 + quad * 8;
        s16x8 wh = *(const s16x8*)(WhT + boff);
        s16x8 wl = *(const s16x8*)(WlT + boff);
        acc[nt] = MFMA16(xh, wh, acc[nt]);
        acc[nt] = MFMA16(xl, wh, acc[nt]);
        acc[nt] = MFMA16(xh, wl, acc[nt]);
      }
    }
    const float* bias = (wv < 2) ? bq : bk;
    short* Oh = (wv < 2) ? Qh : Kh;
    short* Ol = (wv < 2) ? Ql : Kl;
#pragma unroll
    for (int nt = 0; nt < 16; nt++) {
      int col = nt * 16 + lq;
      float bb = bias[col];
#pragma unroll
      for (int r = 0; r < 4; r++) {
        int row = r0 + strip * 16 + quad * 4 + r;
        float val = acc[nt][r] + bb;
        unsigned short hi = f2bf(val);
        unsigned short lo = f2bf(val - bf2f(hi));
        Oh[row * 256 + col] = (short)hi;
        Ol[row * 256 + col] = (short)lo;
      }
    }
  }
  // ---- vT = Wv^T * x^T : each wave does 64 d-rows x 32 t-cols
  {
    const short* WhT = wt + 262144;
    const short* WlT = wt + 327680;
    f32x4 acc[4][2];
#pragma unroll
    for (int mt = 0; mt < 4; mt++)
#pragma unroll
      for (int nt = 0; nt < 2; nt++) acc[mt][nt] = (f32x4){0.f, 0.f, 0.f, 0.f};
#pragma unroll
    for (int c = 0; c < 8; c++) {
      int co = c * 32 + quad * 8;
      s16x8 xh0 = *(const s16x8*)&X[lq * 264 + co];
      s16x8 xl0 = *(const s16x8*)&X[8448 + lq * 264 + co];
      s16x8 xh1 = *(const s16x8*)&X[(16 + lq) * 264 + co];
      s16x8 xl1 = *(const s16x8*)&X[8448 + (16 + lq) * 264 + co];
#pragma unroll
      for (int mt = 0; mt < 4; mt++) {
        int aoff = (wv * 64 + mt * 16 + lq) * 256 + co;
        s16x8 wh = *(const s16x8*)(WhT + aoff);
        s16x8 wl = *(const s16x8*)(WlT + aoff);
        acc[mt][0] = MFMA16(wh, xh0, acc[mt][0]);
        acc[mt][0] = MFMA16(wl, xh0, acc[mt][0]);
        acc[mt][0] = MFMA16(wh, xl0, acc[mt][0]);
        acc[mt][1] = MFMA16(wh, xh1, acc[mt][1]);
        acc[mt][1] = MFMA16(wl, xh1, acc[mt][1]);
        acc[mt][1] = MFMA16(wh, xl1, acc[mt][1]);
      }
    }
#pragma unroll
    for (int mt = 0; mt < 4; mt++) {
#pragma unroll
      for (int r = 0; r < 4; r++) {
        int drow = wv * 64 + mt * 16 + quad * 4 + r;
        float bb = bv[drow];
#pragma unroll
        for (int nt = 0; nt < 2; nt++) {
          float val = acc[mt][nt][r] + bb;
          Vt[(bidx * 256 + drow) * 8192 + tl0 + nt * 16 + lq] = (short)f2bf(val);
        }
      }
    }
  }
}

// ---------------- kernel 3: flash attention ----------------
// 256 blocks: (b, t0 tile of 64). 4 waves, each 16 q-rows. s-tiles of 32.
__global__ __launch_bounds__(256, 1)
void attn_kernel(const short* __restrict__ Qh, const short* __restrict__ Ql,
                 const short* __restrict__ Kh, const short* __restrict__ Kl,
                 const short* __restrict__ Vt,
                 float* __restrict__ out) {
  __shared__ short sm[29696];         // 59392 B
  short* KhL = sm;                    // [32][264]
  short* KlL = sm + 8448;             // [32][264]
  short* VtL = sm + 16896;            // [256][40]
  short* PL  = sm + 27136;            // [64][40]
  int tid = threadIdx.x;
  int lane = tid & 63, wv = tid >> 6, quad = lane >> 4, lq = lane & 15;
  int blk = blockIdx.x;
  int b = blk >> 7;
  int t0 = (blk & 127) * 64;
  int row0g = b * 8192 + t0;

  // Q fragments resident in registers (16 rows per wave, K=256)
  s16x8 qh[8], ql[8];
  {
    int qoff = (row0g + wv * 16 + lq) * 256 + quad * 8;
#pragma unroll
    for (int c = 0; c < 8; c++) {
      qh[c] = *(const s16x8*)(Qh + qoff + c * 32);
      ql[c] = *(const s16x8*)(Ql + qoff + c * 32);
    }
  }
  float m_[4], l_[4];
#pragma unroll
  for (int r = 0; r < 4; r++) { m_[r] = -__builtin_inff(); l_[r] = 0.f; }
  f32x4 Oacc[16];
#pragma unroll
  for (int dt = 0; dt < 16; dt++) Oacc[dt] = (f32x4){0.f, 0.f, 0.f, 0.f};

  // prefetch tile 0 into registers
  u32x4 kh_r[4], kl_r[4], vt_r[4];
#pragma unroll
  for (int i = 0; i < 4; i++) {
    int L = i * 256 + tid;
    int s = L >> 5, g = L & 31;
    int d = L >> 2, g2 = L & 3;
    kh_r[i] = *(const u32x4*)(Kh + (b * 8192 + s) * 256 + g * 8);
    kl_r[i] = *(const u32x4*)(Kl + (b * 8192 + s) * 256 + g * 8);
    vt_r[i] = *(const u32x4*)(Vt + (b * 256 + d) * 8192 + g2 * 8);
  }

  for (int it = 0; it < 256; it++) {
    // commit prefetched tile to LDS
#pragma unroll
    for (int i = 0; i < 4; i++) {
      int L = i * 256 + tid;
      int s = L >> 5, g = L & 31;
      int d = L >> 2, g2 = L & 3;
      *(u32x4*)&KhL[s * 264 + g * 8] = kh_r[i];
      *(u32x4*)&KlL[s * 264 + g * 8] = kl_r[i];
      *(u32x4*)&VtL[d * 40 + g2 * 8] = vt_r[i];
    }
    __syncthreads();
    // prefetch next tile (global loads overlap with compute below)
    {
      int s0n = ((it + 1) & 255) * 32;
#pragma unroll
      for (int i = 0; i < 4; i++) {
        int L = i * 256 + tid;
        int s = L >> 5, g = L & 31;
        int d = L >> 2, g2 = L & 3;
        kh_r[i] = *(const u32x4*)(Kh + (b * 8192 + s0n + s) * 256 + g * 8);
        kl_r[i] = *(const u32x4*)(Kl + (b * 8192 + s0n + s) * 256 + g * 8);
        vt_r[i] = *(const u32x4*)(Vt + (b * 256 + d) * 8192 + s0n + g2 * 8);
      }
    }
    // S = Q K^T, 3-term compensated bf16
    f32x4 a0 = (f32x4){0.f, 0.f, 0.f, 0.f};
    f32x4 a1 = (f32x4){0.f, 0.f, 0.f, 0.f};
#pragma unroll
    for (int c = 0; c < 8; c++) {
      int co = c * 32 + quad * 8;
      s16x8 kh0 = *(const s16x8*)&KhL[lq * 264 + co];
      s16x8 kh1 = *(const s16x8*)&KhL[(16 + lq) * 264 + co];
      s16x8 kl0 = *(const s16x8*)&KlL[lq * 264 + co];
      s16x8 kl1 = *(const s16x8*)&KlL[(16 + lq) * 264 + co];
      a0 = MFMA16(qh[c], kh0, a0);
      a1 = MFMA16(qh[c], kh1, a1);
      a0 = MFMA16(ql[c], kh0, a0);
      a1 = MFMA16(ql[c], kh1, a1);
      a0 = MFMA16(qh[c], kl0, a0);
      a1 = MFMA16(qh[c], kl1, a1);
    }
    // online softmax (fp32); rows r map to C/D row = quad*4+r
    float p0[4], p1[4], alpha[4];
#pragma unroll
    for (int r = 0; r < 4; r++) {
      float mx = fmaxf(a0[r], a1[r]);
      mx = fmaxf(mx, __shfl_xor(mx, 1));
      mx = fmaxf(mx, __shfl_xor(mx, 2));
      mx = fmaxf(mx, __shfl_xor(mx, 4));
      mx = fmaxf(mx, __shfl_xor(mx, 8));
      float mn = fmaxf(m_[r], mx);
      alpha[r] = __expf(m_[r] - mn);
      m_[r] = mn;
      p0[r] = __expf(a0[r] - mn);
      p1[r] = __expf(a1[r] - mn);
      float rs = p0[r] + p1[r];
      rs += __shfl_xor(rs, 1);
      rs += __shfl_xor(rs, 2);
      rs += __shfl_xor(rs, 4);
      rs += __shfl_xor(rs, 8);
      l_[r] = l_[r] * alpha[r] + rs;
    }
    // P -> LDS (wave-private rows; same-wave RAW handled by lgkmcnt)
#pragma unroll
    for (int r = 0; r < 4; r++) {
      int prow = (wv * 16 + quad * 4 + r) * 40;
      PL[prow + lq] = (short)f2bf(p0[r]);
      PL[prow + 16 + lq] = (short)f2bf(p1[r]);
    }
    // rescale O by alpha (skip when whole wave's rows unchanged)
    int sk = (alpha[0] == 1.f) && (alpha[1] == 1.f) && (alpha[2] == 1.f) && (alpha[3] == 1.f);
    if (!__all(sk)) {
#pragma unroll
      for (int dt = 0; dt < 16; dt++) {
#pragma unroll
        for (int r = 0; r < 4; r++) Oacc[dt][r] *= alpha[r];
      }
    }
    // O += P V
    s16x8 pf = *(const s16x8*)&PL[(wv * 16 + lq) * 40 + quad * 8];
#pragma unroll
    for (int dt = 0; dt < 16; dt++) {
      s16x8 vf = *(const s16x8*)&VtL[(dt * 16 + lq) * 40 + quad * 8];
      Oacc[dt] = MFMA16(pf, vf, Oacc[dt]);
    }
    __syncthreads();
  }
  // epilogue
  float inv[4];
#pragma unroll
  for (int r = 0; r < 4; r++) inv[r] = 1.f / l_[r];
#pragma unroll
  for (int dt = 0; dt < 16; dt++) {
#pragma unroll
    for (int r = 0; r < 4; r++) {
      int row = row0g + wv * 16 + quad * 4 + r;
      out[row * 256 + dt * 16 + lq] = Oacc[dt][r] * inv[r];
    }
  }
}

// ---------------- launcher ----------------
extern "C" void kernel_launch(void* const* d_in, const int* in_sizes, int n_in,
                              void* d_out, int out_size, void* d_ws, size_t ws_size,
                              hipStream_t stream) {
  const float* x  = (const float*)d_in[0];
  const float* Wq = (const float*)d_in[1];
  const float* bq = (const float*)d_in[2];
  const float* Wk = (const float*)d_in[3];
  const float* bk = (const float*)d_in[4];
  const float* Wv = (const float*)d_in[5];
  const float* bv = (const float*)d_in[6];
  float* out = (float*)d_out;
  short* ws = (short*)d_ws;
  // ws layout (shorts): wt 393216 | Qh 4194304 | Ql | Kh | Kl | Vt  (~41 MB)
  short* wt = ws;
  short* Qh = ws + 393216;
  short* Ql = Qh + 4194304;
  short* Kh = Ql + 4194304;
  short* Kl = Kh + 4194304;
  short* Vt = Kl + 4194304;
  hipLaunchKernelGGL(wtrans_kernel, dim3(768), dim3(256), 0, stream, Wq, Wk, Wv, wt);
  hipLaunchKernelGGL(qkv_kernel, dim3(512), dim3(256), 0, stream,
                     x, bq, bk, bv, wt, Qh, Ql, Kh, Kl, Vt);
  hipLaunchKernelGGL(attn_kernel, dim3(256), dim3(256), 0, stream,
                     Qh, Ql, Kh, Kl, Vt, out);
}

// Round 2
// 708.972 us; speedup vs baseline: 1.0497x; 1.0497x over previous
//
#include <hip/hip_runtime.h>
#include <stdint.h>

// ---- types ----
typedef __attribute__((ext_vector_type(4))) float f32x4;
typedef __attribute__((ext_vector_type(8))) short s16x8;
typedef __attribute__((ext_vector_type(4))) short s16x4;
typedef __attribute__((ext_vector_type(4))) unsigned int u32x4;

#define MFMA16(a, b, c) __builtin_amdgcn_mfma_f32_16x16x32_bf16((a), (b), (c), 0, 0, 0)

// B=2, T=8192, D=256; rows = B*T = 16384 flat.

__device__ __forceinline__ unsigned short f2bf(float f) {
  unsigned int u = __float_as_uint(f);
  u += 0x7FFFu + ((u >> 16) & 1u);  // RNE
  return (unsigned short)(u >> 16);
}
__device__ __forceinline__ float bf2f(unsigned short h) {
  return __uint_as_float(((unsigned int)h) << 16);
}

// ---------------- kernel 1: weight transpose + hi/lo split ----------------
__global__ void wtrans_kernel(const float* __restrict__ Wq,
                              const float* __restrict__ Wk,
                              const float* __restrict__ Wv,
                              short* __restrict__ wt) {
  int idx = blockIdx.x * 256 + threadIdx.x;   // 768 blocks * 256
  int w = idx >> 16;
  int rc = idx & 65535;
  int d = rc >> 8;
  int n = rc & 255;
  const float* Ws = (w == 0) ? Wq : ((w == 1) ? Wk : Wv);
  float v = Ws[rc];
  unsigned short hi = f2bf(v);
  unsigned short lo = f2bf(v - bf2f(hi));
  short* th = wt + w * 131072;
  th[n * 256 + d] = (short)hi;
  th[65536 + n * 256 + d] = (short)lo;
}

// ---------------- kernel 2: QKV projection (3-term bf16 MFMA) ----------------
__global__ __launch_bounds__(256, 2)
void qkv_kernel(const float* __restrict__ x,
                const float* __restrict__ bq,
                const float* __restrict__ bk,
                const float* __restrict__ bv,
                const short* __restrict__ wt,
                short* __restrict__ Qh, short* __restrict__ Ql,
                short* __restrict__ Kh, short* __restrict__ Kl,
                short* __restrict__ Vt) {
  __shared__ short X[16896];
  int tid = threadIdx.x;
  int r0 = blockIdx.x * 32;
  int bidx = r0 >> 13;
  int tl0 = r0 & 8191;
#pragma unroll
  for (int i = 0; i < 8; i++) {
    int E = i * 1024 + tid * 4;
    int r = E >> 8, col = E & 255;
    f32x4 v = *(const f32x4*)(x + (size_t)(r0 + r) * 256 + col);
    s16x4 h, lo;
#pragma unroll
    for (int j = 0; j < 4; j++) {
      unsigned short hh = f2bf(v[j]);
      h[j] = (short)hh;
      lo[j] = (short)f2bf(v[j] - bf2f(hh));
    }
    *(s16x4*)&X[r * 264 + col] = h;
    *(s16x4*)&X[8448 + r * 264 + col] = lo;
  }
  __syncthreads();

  int lane = tid & 63, wv = tid >> 6;
  int quad = lane >> 4, lq = lane & 15;

  {
    int strip = wv & 1;
    const short* WhT = wt + ((wv < 2) ? 0 : 131072);
    const short* WlT = WhT + 65536;
    f32x4 acc[16];
#pragma unroll
    for (int nt = 0; nt < 16; nt++) acc[nt] = (f32x4){0.f, 0.f, 0.f, 0.f};
    int arow = (strip * 16 + lq) * 264 + quad * 8;
#pragma unroll
    for (int c = 0; c < 8; c++) {
      s16x8 xh = *(const s16x8*)&X[arow + c * 32];
      s16x8 xl = *(const s16x8*)&X[8448 + arow + c * 32];
#pragma unroll
      for (int nt = 0; nt < 16; nt++) {
        int boff = (nt * 16 + lq) * 256 + c * 32 + quad * 8;
        s16x8 wh = *(const s16x8*)(WhT + boff);
        s16x8 wl = *(const s16x8*)(WlT + boff);
        acc[nt] = MFMA16(xh, wh, acc[nt]);
        acc[nt] = MFMA16(xl, wh, acc[nt]);
        acc[nt] = MFMA16(xh, wl, acc[nt]);
      }
    }
    const float* bias = (wv < 2) ? bq : bk;
    short* Oh = (wv < 2) ? Qh : Kh;
    short* Ol = (wv < 2) ? Ql : Kl;
#pragma unroll
    for (int nt = 0; nt < 16; nt++) {
      int col = nt * 16 + lq;
      float bb = bias[col];
#pragma unroll
      for (int r = 0; r < 4; r++) {
        int row = r0 + strip * 16 + quad * 4 + r;
        float val = acc[nt][r] + bb;
        unsigned short hi = f2bf(val);
        unsigned short lo = f2bf(val - bf2f(hi));
        Oh[row * 256 + col] = (short)hi;
        Ol[row * 256 + col] = (short)lo;
      }
    }
  }
  {
    const short* WhT = wt + 262144;
    const short* WlT = wt + 327680;
    f32x4 acc[4][2];
#pragma unroll
    for (int mt = 0; mt < 4; mt++)
#pragma unroll
      for (int nt = 0; nt < 2; nt++) acc[mt][nt] = (f32x4){0.f, 0.f, 0.f, 0.f};
#pragma unroll
    for (int c = 0; c < 8; c++) {
      int co = c * 32 + quad * 8;
      s16x8 xh0 = *(const s16x8*)&X[lq * 264 + co];
      s16x8 xl0 = *(const s16x8*)&X[8448 + lq * 264 + co];
      s16x8 xh1 = *(const s16x8*)&X[(16 + lq) * 264 + co];
      s16x8 xl1 = *(const s16x8*)&X[8448 + (16 + lq) * 264 + co];
#pragma unroll
      for (int mt = 0; mt < 4; mt++) {
        int aoff = (wv * 64 + mt * 16 + lq) * 256 + co;
        s16x8 wh = *(const s16x8*)(WhT + aoff);
        s16x8 wl = *(const s16x8*)(WlT + aoff);
        acc[mt][0] = MFMA16(wh, xh0, acc[mt][0]);
        acc[mt][0] = MFMA16(wl, xh0, acc[mt][0]);
        acc[mt][0] = MFMA16(wh, xl0, acc[mt][0]);
        acc[mt][1] = MFMA16(wh, xh1, acc[mt][1]);
        acc[mt][1] = MFMA16(wl, xh1, acc[mt][1]);
        acc[mt][1] = MFMA16(wh, xl1, acc[mt][1]);
      }
    }
#pragma unroll
    for (int mt = 0; mt < 4; mt++) {
#pragma unroll
      for (int r = 0; r < 4; r++) {
        int drow = wv * 64 + mt * 16 + quad * 4 + r;
        float bb = bv[drow];
#pragma unroll
        for (int nt = 0; nt < 2; nt++) {
          float val = acc[mt][nt][r] + bb;
          Vt[(bidx * 256 + drow) * 8192 + tl0 + nt * 16 + lq] = (short)f2bf(val);
        }
      }
    }
  }
}

// ---------------- kernel 3: flash attention ----------------
// 256 blocks: (b, t0 tile of 64). 8 waves: strip = wv&3 (16 q-rows),
// shalf = wv>>2 (which 16 of the 32 staged s-cols). Independent online
// softmax per wave over its s-stripe; pair-merge at the end.
__global__ __launch_bounds__(512, 2)
void attn_kernel(const short* __restrict__ Qh, const short* __restrict__ Ql,
                 const short* __restrict__ Kh, const short* __restrict__ Kl,
                 const short* __restrict__ Vt,
                 float* __restrict__ out) {
  __shared__ short sm[32256];         // 64512 B
  short* KhL = sm;                    // [32][264]
  short* KlL = sm + 8448;             // [32][264]
  short* VtL = sm + 16896;            // [256][40]
  short* PLb = sm + 27136;            // 8 waves x [16][40]
  int tid = threadIdx.x;
  int lane = tid & 63, wv = tid >> 6, quad = lane >> 4, lq = lane & 15;
  int strip = wv & 3, shalf = wv >> 2;
  short* PL = PLb + wv * 640;
  int blk = blockIdx.x;
  int b = blk >> 7;
  int t0 = (blk & 127) * 64;
  int row0g = b * 8192 + t0;

  // zero the partner-half of this wave's private P (stays zero forever)
#pragma unroll
  for (int r = 0; r < 4; r++)
    PL[(quad * 4 + r) * 40 + (1 - shalf) * 16 + lq] = 0;

  // Q fragments resident in registers (16 rows per wave, K=256)
  s16x8 qh[8], ql[8];
  {
    int qoff = (row0g + strip * 16 + lq) * 256 + quad * 8;
#pragma unroll
    for (int c = 0; c < 8; c++) {
      qh[c] = *(const s16x8*)(Qh + qoff + c * 32);
      ql[c] = *(const s16x8*)(Ql + qoff + c * 32);
    }
  }
  float m_[4], l_[4];
#pragma unroll
  for (int r = 0; r < 4; r++) { m_[r] = -__builtin_inff(); l_[r] = 0.f; }
  f32x4 Oacc[16];
#pragma unroll
  for (int dt = 0; dt < 16; dt++) Oacc[dt] = (f32x4){0.f, 0.f, 0.f, 0.f};

  // prefetch tile 0 into registers (6 x b128 per thread)
  u32x4 kh_r[2], kl_r[2], vt_r[2];
#pragma unroll
  for (int i = 0; i < 2; i++) {
    int L = i * 512 + tid;
    int s = L >> 5, g = L & 31;
    int d = L >> 2, g2 = L & 3;
    kh_r[i] = *(const u32x4*)(Kh + (b * 8192 + s) * 256 + g * 8);
    kl_r[i] = *(const u32x4*)(Kl + (b * 8192 + s) * 256 + g * 8);
    vt_r[i] = *(const u32x4*)(Vt + (b * 256 + d) * 8192 + g2 * 8);
  }

  for (int it = 0; it < 256; it++) {
    // commit prefetched tile to LDS
#pragma unroll
    for (int i = 0; i < 2; i++) {
      int L = i * 512 + tid;
      int s = L >> 5, g = L & 31;
      int d = L >> 2, g2 = L & 3;
      *(u32x4*)&KhL[s * 264 + g * 8] = kh_r[i];
      *(u32x4*)&KlL[s * 264 + g * 8] = kl_r[i];
      *(u32x4*)&VtL[d * 40 + g2 * 8] = vt_r[i];
    }
    __syncthreads();
    // prefetch next tile (overlaps with compute below)
    {
      int s0n = ((it + 1) & 255) * 32;
#pragma unroll
      for (int i = 0; i < 2; i++) {
        int L = i * 512 + tid;
        int s = L >> 5, g = L & 31;
        int d = L >> 2, g2 = L & 3;
        kh_r[i] = *(const u32x4*)(Kh + (b * 8192 + s0n + s) * 256 + g * 8);
        kl_r[i] = *(const u32x4*)(Kl + (b * 8192 + s0n + s) * 256 + g * 8);
        vt_r[i] = *(const u32x4*)(Vt + (b * 256 + d) * 8192 + s0n + g2 * 8);
      }
    }
    // S = Q K^T for this wave's 16 s-cols; 3 independent term-chains
    f32x4 ahh = (f32x4){0.f, 0.f, 0.f, 0.f};
    f32x4 alh = (f32x4){0.f, 0.f, 0.f, 0.f};
    f32x4 ahl = (f32x4){0.f, 0.f, 0.f, 0.f};
    int krow = (shalf * 16 + lq) * 264 + quad * 8;
#pragma unroll
    for (int c = 0; c < 8; c++) {
      s16x8 kh0 = *(const s16x8*)&KhL[krow + c * 32];
      s16x8 kl0 = *(const s16x8*)&KlL[krow + c * 32];
      ahh = MFMA16(qh[c], kh0, ahh);
      alh = MFMA16(ql[c], kh0, alh);
      ahl = MFMA16(qh[c], kl0, ahl);
    }
    f32x4 a;
#pragma unroll
    for (int r = 0; r < 4; r++) a[r] = ahh[r] + alh[r] + ahl[r];
    // online softmax over this wave's 16 cols
    float p[4], alpha[4];
#pragma unroll
    for (int r = 0; r < 4; r++) {
      float mx = a[r];
      mx = fmaxf(mx, __shfl_xor(mx, 1));
      mx = fmaxf(mx, __shfl_xor(mx, 2));
      mx = fmaxf(mx, __shfl_xor(mx, 4));
      mx = fmaxf(mx, __shfl_xor(mx, 8));
      float mn = fmaxf(m_[r], mx);
      alpha[r] = __expf(m_[r] - mn);
      m_[r] = mn;
      p[r] = __expf(a[r] - mn);
      float rs = p[r];
      rs += __shfl_xor(rs, 1);
      rs += __shfl_xor(rs, 2);
      rs += __shfl_xor(rs, 4);
      rs += __shfl_xor(rs, 8);
      l_[r] = l_[r] * alpha[r] + rs;
    }
    // write own-half P (wave-private region; same-wave RAW via lgkmcnt)
#pragma unroll
    for (int r = 0; r < 4; r++)
      PL[(quad * 4 + r) * 40 + shalf * 16 + lq] = (short)f2bf(p[r]);
    // rescale O by alpha (skip when whole wave's rows unchanged)
    int sk = (alpha[0] == 1.f) && (alpha[1] == 1.f) && (alpha[2] == 1.f) && (alpha[3] == 1.f);
    if (!__all(sk)) {
#pragma unroll
      for (int dt = 0; dt < 16; dt++) {
#pragma unroll
        for (int r = 0; r < 4; r++) Oacc[dt][r] *= alpha[r];
      }
    }
    // O += P V  (K=32 with partner half of P zeroed)
    s16x8 pf = *(const s16x8*)&PL[lq * 40 + quad * 8];
#pragma unroll
    for (int dt = 0; dt < 16; dt++) {
      s16x8 vf = *(const s16x8*)&VtL[(dt * 16 + lq) * 40 + quad * 8];
      Oacc[dt] = MFMA16(pf, vf, Oacc[dt]);
    }
    __syncthreads();
  }

  // ---- pair merge (wv <-> wv^4) via LDS, 2 passes of 8 dt ----
  float* Ob = (float*)sm;             // [64][132] fp32
  float* Ml = (float*)sm + 64 * 132;  // m [64], l [64]
  float a0s[4], a1s[4], linv[4];
#pragma unroll
  for (int half = 0; half < 2; half++) {
    if (shalf == 1) {
#pragma unroll
      for (int dt2 = 0; dt2 < 8; dt2++) {
        int dt = half * 8 + dt2;
#pragma unroll
        for (int r = 0; r < 4; r++)
          Ob[(strip * 16 + quad * 4 + r) * 132 + dt2 * 16 + lq] = Oacc[dt][r];
      }
      if (half == 0 && lq == 0) {
#pragma unroll
        for (int r = 0; r < 4; r++) {
          int rb = strip * 16 + quad * 4 + r;
          Ml[rb] = m_[r];
          Ml[64 + rb] = l_[r];
        }
      }
    }
    __syncthreads();
    if (shalf == 0) {
      if (half == 0) {
#pragma unroll
        for (int r = 0; r < 4; r++) {
          int rb = strip * 16 + quad * 4 + r;
          float m1 = Ml[rb], l1 = Ml[64 + rb];
          float mm = fmaxf(m_[r], m1);
          a0s[r] = __expf(m_[r] - mm);
          a1s[r] = __expf(m1 - mm);
          linv[r] = 1.f / (l_[r] * a0s[r] + l1 * a1s[r]);
        }
      }
#pragma unroll
      for (int dt2 = 0; dt2 < 8; dt2++) {
        int dt = half * 8 + dt2;
#pragma unroll
        for (int r = 0; r < 4; r++) {
          int rb = strip * 16 + quad * 4 + r;
          float o1 = Ob[rb * 132 + dt2 * 16 + lq];
          int row = row0g + rb;
          out[row * 256 + dt * 16 + lq] =
              (Oacc[dt][r] * a0s[r] + o1 * a1s[r]) * linv[r];
        }
      }
    }
    __syncthreads();
  }
}

// ---------------- launcher ----------------
extern "C" void kernel_launch(void* const* d_in, const int* in_sizes, int n_in,
                              void* d_out, int out_size, void* d_ws, size_t ws_size,
                              hipStream_t stream) {
  const float* x  = (const float*)d_in[0];
  const float* Wq = (const float*)d_in[1];
  const float* bq = (const float*)d_in[2];
  const float* Wk = (const float*)d_in[3];
  const float* bk = (const float*)d_in[4];
  const float* Wv = (const float*)d_in[5];
  const float* bv = (const float*)d_in[6];
  float* out = (float*)d_out;
  short* ws = (short*)d_ws;
  short* wt = ws;
  short* Qh = ws + 393216;
  short* Ql = Qh + 4194304;
  short* Kh = Ql + 4194304;
  short* Kl = Kh + 4194304;
  short* Vt = Kl + 4194304;
  hipLaunchKernelGGL(wtrans_kernel, dim3(768), dim3(256), 0, stream, Wq, Wk, Wv, wt);
  hipLaunchKernelGGL(qkv_kernel, dim3(512), dim3(256), 0, stream,
                     x, bq, bk, bv, wt, Qh, Ql, Kh, Kl, Vt);
  hipLaunchKernelGGL(attn_kernel, dim3(256), dim3(512), 0, stream,
                     Qh, Ql, Kh, Kl, Vt, out);
}

// Round 3
// 581.005 us; speedup vs baseline: 1.2809x; 1.2202x over previous
//
#include <hip/hip_runtime.h>
#include <stdint.h>

// ---- types ----
typedef __attribute__((ext_vector_type(4))) float f32x4;
typedef __attribute__((ext_vector_type(8))) short s16x8;
typedef __attribute__((ext_vector_type(4))) short s16x4;
typedef __attribute__((ext_vector_type(4))) unsigned int u32x4;

#define MFMA16(a, b, c) __builtin_amdgcn_mfma_f32_16x16x32_bf16((a), (b), (c), 0, 0, 0)

// B=2, T=8192, D=256; rows = B*T = 16384 flat.

__device__ __forceinline__ unsigned short f2bf(float f) {
  unsigned int u = __float_as_uint(f);
  u += 0x7FFFu + ((u >> 16) & 1u);  // RNE
  return (unsigned short)(u >> 16);
}
__device__ __forceinline__ float bf2f(unsigned short h) {
  return __uint_as_float(((unsigned int)h) << 16);
}

// ---------------- kernel 1: weight transpose + hi/lo split ----------------
__global__ void wtrans_kernel(const float* __restrict__ Wq,
                              const float* __restrict__ Wk,
                              const float* __restrict__ Wv,
                              short* __restrict__ wt) {
  int idx = blockIdx.x * 256 + threadIdx.x;   // 768 blocks * 256
  int w = idx >> 16;
  int rc = idx & 65535;
  int d = rc >> 8;
  int n = rc & 255;
  const float* Ws = (w == 0) ? Wq : ((w == 1) ? Wk : Wv);
  float v = Ws[rc];
  unsigned short hi = f2bf(v);
  unsigned short lo = f2bf(v - bf2f(hi));
  short* th = wt + w * 131072;
  th[n * 256 + d] = (short)hi;
  th[65536 + n * 256 + d] = (short)lo;
}

// ---------------- kernel 2: QKV projection (3-term bf16 MFMA) ----------------
__global__ __launch_bounds__(256, 2)
void qkv_kernel(const float* __restrict__ x,
                const float* __restrict__ bq,
                const float* __restrict__ bk,
                const float* __restrict__ bv,
                const short* __restrict__ wt,
                short* __restrict__ Qh, short* __restrict__ Ql,
                short* __restrict__ Kh, short* __restrict__ Kl,
                short* __restrict__ Vt) {
  __shared__ short X[16896];
  int tid = threadIdx.x;
  int r0 = blockIdx.x * 32;
  int bidx = r0 >> 13;
  int tl0 = r0 & 8191;
#pragma unroll
  for (int i = 0; i < 8; i++) {
    int E = i * 1024 + tid * 4;
    int r = E >> 8, col = E & 255;
    f32x4 v = *(const f32x4*)(x + (size_t)(r0 + r) * 256 + col);
    s16x4 h, lo;
#pragma unroll
    for (int j = 0; j < 4; j++) {
      unsigned short hh = f2bf(v[j]);
      h[j] = (short)hh;
      lo[j] = (short)f2bf(v[j] - bf2f(hh));
    }
    *(s16x4*)&X[r * 264 + col] = h;
    *(s16x4*)&X[8448 + r * 264 + col] = lo;
  }
  __syncthreads();

  int lane = tid & 63, wv = tid >> 6;
  int quad = lane >> 4, lq = lane & 15;

  {
    int strip = wv & 1;
    const short* WhT = wt + ((wv < 2) ? 0 : 131072);
    const short* WlT = WhT + 65536;
    f32x4 acc[16];
#pragma unroll
    for (int nt = 0; nt < 16; nt++) acc[nt] = (f32x4){0.f, 0.f, 0.f, 0.f};
    int arow = (strip * 16 + lq) * 264 + quad * 8;
#pragma unroll
    for (int c = 0; c < 8; c++) {
      s16x8 xh = *(const s16x8*)&X[arow + c * 32];
      s16x8 xl = *(const s16x8*)&X[8448 + arow + c * 32];
#pragma unroll
      for (int nt = 0; nt < 16; nt++) {
        int boff = (nt * 16 + lq) * 256 + c * 32 + quad * 8;
        s16x8 wh = *(const s16x8*)(WhT + boff);
        s16x8 wl = *(const s16x8*)(WlT + boff);
        acc[nt] = MFMA16(xh, wh, acc[nt]);
        acc[nt] = MFMA16(xl, wh, acc[nt]);
        acc[nt] = MFMA16(xh, wl, acc[nt]);
      }
    }
    const float* bias = (wv < 2) ? bq : bk;
    short* Oh = (wv < 2) ? Qh : Kh;
    short* Ol = (wv < 2) ? Ql : Kl;
#pragma unroll
    for (int nt = 0; nt < 16; nt++) {
      int col = nt * 16 + lq;
      float bb = bias[col];
#pragma unroll
      for (int r = 0; r < 4; r++) {
        int row = r0 + strip * 16 + quad * 4 + r;
        float val = acc[nt][r] + bb;
        unsigned short hi = f2bf(val);
        unsigned short lo = f2bf(val - bf2f(hi));
        Oh[row * 256 + col] = (short)hi;
        Ol[row * 256 + col] = (short)lo;
      }
    }
  }
  {
    const short* WhT = wt + 262144;
    const short* WlT = wt + 327680;
    f32x4 acc[4][2];
#pragma unroll
    for (int mt = 0; mt < 4; mt++)
#pragma unroll
      for (int nt = 0; nt < 2; nt++) acc[mt][nt] = (f32x4){0.f, 0.f, 0.f, 0.f};
#pragma unroll
    for (int c = 0; c < 8; c++) {
      int co = c * 32 + quad * 8;
      s16x8 xh0 = *(const s16x8*)&X[lq * 264 + co];
      s16x8 xl0 = *(const s16x8*)&X[8448 + lq * 264 + co];
      s16x8 xh1 = *(const s16x8*)&X[(16 + lq) * 264 + co];
      s16x8 xl1 = *(const s16x8*)&X[8448 + (16 + lq) * 264 + co];
#pragma unroll
      for (int mt = 0; mt < 4; mt++) {
        int aoff = (wv * 64 + mt * 16 + lq) * 256 + co;
        s16x8 wh = *(const s16x8*)(WhT + aoff);
        s16x8 wl = *(const s16x8*)(WlT + aoff);
        acc[mt][0] = MFMA16(wh, xh0, acc[mt][0]);
        acc[mt][0] = MFMA16(wl, xh0, acc[mt][0]);
        acc[mt][0] = MFMA16(wh, xl0, acc[mt][0]);
        acc[mt][1] = MFMA16(wh, xh1, acc[mt][1]);
        acc[mt][1] = MFMA16(wl, xh1, acc[mt][1]);
        acc[mt][1] = MFMA16(wh, xl1, acc[mt][1]);
      }
    }
#pragma unroll
    for (int mt = 0; mt < 4; mt++) {
#pragma unroll
      for (int r = 0; r < 4; r++) {
        int drow = wv * 64 + mt * 16 + quad * 4 + r;
        float bb = bv[drow];
#pragma unroll
        for (int nt = 0; nt < 2; nt++) {
          float val = acc[mt][nt][r] + bb;
          Vt[(bidx * 256 + drow) * 8192 + tl0 + nt * 16 + lq] = (short)f2bf(val);
        }
      }
    }
  }
}

// ---------------- kernel 3: flash attention ----------------
// 256 blocks: (b, t0 tile of 64). 8 waves: strip = wv&3 (16 q-rows),
// shalf = wv>>2 (32 of the 64 staged s-cols). S_TILE=64, s_w=32:
// PV runs K=32 fully used; l comes from a ones-column in V (dt=16).
__global__ __launch_bounds__(512, 2)
void attn_kernel(const short* __restrict__ Qh, const short* __restrict__ Ql,
                 const short* __restrict__ Kh, const short* __restrict__ Kl,
                 const short* __restrict__ Vt,
                 float* __restrict__ out) {
  __shared__ short sm[57416];          // 114832 B
  short* KhL = sm;                     // [64][264]
  short* KlL = sm + 16896;             // [64][264]
  short* VtL = sm + 33792;             // [257][72] (row 256 = ones)
  short* PLb = sm + 52296;             // 8 waves x [16][40]
  int tid = threadIdx.x;
  int lane = tid & 63, wv = tid >> 6, quad = lane >> 4, lq = lane & 15;
  int strip = wv & 3, shalf = wv >> 2;
  short* PL = PLb + wv * 640;
  int blk = blockIdx.x;
  int b = blk >> 7;
  int t0 = (blk & 127) * 64;
  int row0g = b * 8192 + t0;

  // ones row of VtL (row 256, 64 cols) — staged once, never overwritten
  if (tid < 8) {
    u32x4 ones;
    ones[0] = ones[1] = ones[2] = ones[3] = 0x3F803F80u;
    *(u32x4*)&VtL[256 * 72 + tid * 8] = ones;
  }

  // Q fragments resident in registers (16 rows per wave, K=256)
  s16x8 qh[8], ql[8];
  {
    int qoff = (row0g + strip * 16 + lq) * 256 + quad * 8;
#pragma unroll
    for (int c = 0; c < 8; c++) {
      qh[c] = *(const s16x8*)(Qh + qoff + c * 32);
      ql[c] = *(const s16x8*)(Ql + qoff + c * 32);
    }
  }
  float m_[4];
#pragma unroll
  for (int r = 0; r < 4; r++) m_[r] = -__builtin_inff();
  f32x4 Oacc[17];                      // [16] = ones-column => l
#pragma unroll
  for (int dt = 0; dt < 17; dt++) Oacc[dt] = (f32x4){0.f, 0.f, 0.f, 0.f};

  // prefetch tile 0 into registers (12 x b128 per thread)
  u32x4 kh_r[4], kl_r[4], vt_r[4];
#pragma unroll
  for (int i = 0; i < 4; i++) {
    int L = i * 512 + tid;
    int s = L >> 5, g = L & 31;
    int d = L >> 3, g2 = L & 7;
    kh_r[i] = *(const u32x4*)(Kh + (b * 8192 + s) * 256 + g * 8);
    kl_r[i] = *(const u32x4*)(Kl + (b * 8192 + s) * 256 + g * 8);
    vt_r[i] = *(const u32x4*)(Vt + (b * 256 + d) * 8192 + g2 * 8);
  }

  for (int it = 0; it < 128; it++) {
    // commit prefetched tile to LDS
#pragma unroll
    for (int i = 0; i < 4; i++) {
      int L = i * 512 + tid;
      int s = L >> 5, g = L & 31;
      int d = L >> 3, g2 = L & 7;
      *(u32x4*)&KhL[s * 264 + g * 8] = kh_r[i];
      *(u32x4*)&KlL[s * 264 + g * 8] = kl_r[i];
      *(u32x4*)&VtL[d * 72 + g2 * 8] = vt_r[i];
    }
    __syncthreads();
    // prefetch next tile (overlaps with compute below)
    {
      int s0n = ((it + 1) & 127) * 64;
#pragma unroll
      for (int i = 0; i < 4; i++) {
        int L = i * 512 + tid;
        int s = L >> 5, g = L & 31;
        int d = L >> 3, g2 = L & 7;
        kh_r[i] = *(const u32x4*)(Kh + (b * 8192 + s0n + s) * 256 + g * 8);
        kl_r[i] = *(const u32x4*)(Kl + (b * 8192 + s0n + s) * 256 + g * 8);
        vt_r[i] = *(const u32x4*)(Vt + (b * 256 + d) * 8192 + s0n + g2 * 8);
      }
    }
    // S = Q K^T over this wave's 32 s-cols (2 col-frags), 3-term compensated
    f32x4 ahh0 = (f32x4){0.f, 0.f, 0.f, 0.f}, ahh1 = ahh0;
    f32x4 alh0 = ahh0, alh1 = ahh0, ahl0 = ahh0, ahl1 = ahh0;
    int krowA = (shalf * 32 + lq) * 264;
    int krowB = krowA + 16 * 264;
#pragma unroll
    for (int c = 0; c < 8; c++) {
      int off = c * 32 + quad * 8;
      s16x8 kh0 = *(const s16x8*)&KhL[krowA + off];
      s16x8 kh1 = *(const s16x8*)&KhL[krowB + off];
      s16x8 kl0 = *(const s16x8*)&KlL[krowA + off];
      s16x8 kl1 = *(const s16x8*)&KlL[krowB + off];
      ahh0 = MFMA16(qh[c], kh0, ahh0);
      ahh1 = MFMA16(qh[c], kh1, ahh1);
      alh0 = MFMA16(ql[c], kh0, alh0);
      alh1 = MFMA16(ql[c], kh1, alh1);
      ahl0 = MFMA16(qh[c], kl0, ahl0);
      ahl1 = MFMA16(qh[c], kl1, ahl1);
    }
    f32x4 a0, a1;
#pragma unroll
    for (int r = 0; r < 4; r++) {
      a0[r] = ahh0[r] + alh0[r] + ahl0[r];
      a1[r] = ahh1[r] + alh1[r] + ahl1[r];
    }
    // online softmax over 32 cols (max only; l comes from ones-column)
    float alpha[4];
#pragma unroll
    for (int r = 0; r < 4; r++) {
      float mx = fmaxf(a0[r], a1[r]);
      mx = fmaxf(mx, __shfl_xor(mx, 1));
      mx = fmaxf(mx, __shfl_xor(mx, 2));
      mx = fmaxf(mx, __shfl_xor(mx, 4));
      mx = fmaxf(mx, __shfl_xor(mx, 8));
      float mn = fmaxf(m_[r], mx);
      alpha[r] = __expf(m_[r] - mn);
      m_[r] = mn;
      float p0 = __expf(a0[r] - mn);
      float p1 = __expf(a1[r] - mn);
      int prow = (quad * 4 + r) * 40;
      PL[prow + lq] = (short)f2bf(p0);
      PL[prow + 16 + lq] = (short)f2bf(p1);
    }
    // rescale O (incl. l-column) by alpha; skip when wave-uniform no-op
    int sk = (alpha[0] == 1.f) && (alpha[1] == 1.f) && (alpha[2] == 1.f) && (alpha[3] == 1.f);
    if (!__all(sk)) {
#pragma unroll
      for (int dt = 0; dt < 17; dt++) {
#pragma unroll
        for (int r = 0; r < 4; r++) Oacc[dt][r] *= alpha[r];
      }
    }
    // O += P V, K=32 fully used; dt=16 is the ones row (=> l)
    s16x8 pf = *(const s16x8*)&PL[lq * 40 + quad * 8];
#pragma unroll
    for (int dt = 0; dt < 17; dt++) {
      int vrow = (dt < 16) ? dt * 16 + lq : 256;
      s16x8 vf = *(const s16x8*)&VtL[vrow * 72 + shalf * 32 + quad * 8];
      Oacc[dt] = MFMA16(pf, vf, Oacc[dt]);
    }
    __syncthreads();
  }

  float l_[4];
#pragma unroll
  for (int r = 0; r < 4; r++) l_[r] = Oacc[16][r];

  // ---- pair merge (wv <-> wv^4) via LDS, 2 passes of 8 dt ----
  float* Ob = (float*)sm;             // [64][132] fp32
  float* Ml = (float*)sm + 64 * 132;  // m [64], l [64]
  float a0s[4], a1s[4], linv[4];
#pragma unroll
  for (int half = 0; half < 2; half++) {
    if (shalf == 1) {
#pragma unroll
      for (int dt2 = 0; dt2 < 8; dt2++) {
        int dt = half * 8 + dt2;
#pragma unroll
        for (int r = 0; r < 4; r++)
          Ob[(strip * 16 + quad * 4 + r) * 132 + dt2 * 16 + lq] = Oacc[dt][r];
      }
      if (half == 0 && lq == 0) {
#pragma unroll
        for (int r = 0; r < 4; r++) {
          int rb = strip * 16 + quad * 4 + r;
          Ml[rb] = m_[r];
          Ml[64 + rb] = l_[r];
        }
      }
    }
    __syncthreads();
    if (shalf == 0) {
      if (half == 0) {
#pragma unroll
        for (int r = 0; r < 4; r++) {
          int rb = strip * 16 + quad * 4 + r;
          float m1 = Ml[rb], l1 = Ml[64 + rb];
          float mm = fmaxf(m_[r], m1);
          a0s[r] = __expf(m_[r] - mm);
          a1s[r] = __expf(m1 - mm);
          linv[r] = 1.f / (l_[r] * a0s[r] + l1 * a1s[r]);
        }
      }
#pragma unroll
      for (int dt2 = 0; dt2 < 8; dt2++) {
        int dt = half * 8 + dt2;
#pragma unroll
        for (int r = 0; r < 4; r++) {
          int rb = strip * 16 + quad * 4 + r;
          float o1 = Ob[rb * 132 + dt2 * 16 + lq];
          int row = row0g + rb;
          out[row * 256 + dt * 16 + lq] =
              (Oacc[dt][r] * a0s[r] + o1 * a1s[r]) * linv[r];
        }
      }
    }
    __syncthreads();
  }
}

// ---------------- launcher ----------------
extern "C" void kernel_launch(void* const* d_in, const int* in_sizes, int n_in,
                              void* d_out, int out_size, void* d_ws, size_t ws_size,
                              hipStream_t stream) {
  const float* x  = (const float*)d_in[0];
  const float* Wq = (const float*)d_in[1];
  const float* bq = (const float*)d_in[2];
  const float* Wk = (const float*)d_in[3];
  const float* bk = (const float*)d_in[4];
  const float* Wv = (const float*)d_in[5];
  const float* bv = (const float*)d_in[6];
  float* out = (float*)d_out;
  short* ws = (short*)d_ws;
  short* wt = ws;
  short* Qh = ws + 393216;
  short* Ql = Qh + 4194304;
  short* Kh = Ql + 4194304;
  short* Kl = Kh + 4194304;
  short* Vt = Kl + 4194304;
  hipLaunchKernelGGL(wtrans_kernel, dim3(768), dim3(256), 0, stream, Wq, Wk, Wv, wt);
  hipLaunchKernelGGL(qkv_kernel, dim3(512), dim3(256), 0, stream,
                     x, bq, bk, bv, wt, Qh, Ql, Kh, Kl, Vt);
  hipLaunchKernelGGL(attn_kernel, dim3(256), dim3(512), 0, stream,
                     Qh, Ql, Kh, Kl, Vt, out);
}

// Round 4
// 490.594 us; speedup vs baseline: 1.5170x; 1.1843x over previous
//
#include <hip/hip_runtime.h>
#include <stdint.h>

// ---- types ----
typedef __attribute__((ext_vector_type(4))) float f32x4;
typedef __attribute__((ext_vector_type(8))) short s16x8;
typedef __attribute__((ext_vector_type(4))) short s16x4;
typedef __attribute__((ext_vector_type(4))) unsigned int u32x4;

#define MFMA16(a, b, c) __builtin_amdgcn_mfma_f32_16x16x32_bf16((a), (b), (c), 0, 0, 0)

// B=2, T=8192, D=256; rows = B*T = 16384 flat.

__device__ __forceinline__ unsigned short f2bf(float f) {
  unsigned int u = __float_as_uint(f);
  u += 0x7FFFu + ((u >> 16) & 1u);  // RNE
  return (unsigned short)(u >> 16);
}
__device__ __forceinline__ float bf2f(unsigned short h) {
  return __uint_as_float(((unsigned int)h) << 16);
}

// ---------------- kernel 1: weight transpose + hi/lo split ----------------
__global__ void wtrans_kernel(const float* __restrict__ Wq,
                              const float* __restrict__ Wk,
                              const float* __restrict__ Wv,
                              short* __restrict__ wt) {
  int idx = blockIdx.x * 256 + threadIdx.x;   // 768 blocks * 256
  int w = idx >> 16;
  int rc = idx & 65535;
  int d = rc >> 8;
  int n = rc & 255;
  const float* Ws = (w == 0) ? Wq : ((w == 1) ? Wk : Wv);
  float v = Ws[rc];
  unsigned short hi = f2bf(v);
  unsigned short lo = f2bf(v - bf2f(hi));
  short* th = wt + w * 131072;
  th[n * 256 + d] = (short)hi;
  th[65536 + n * 256 + d] = (short)lo;
}

// ---------------- kernel 2: QKV projection (3-term bf16 MFMA) ----------------
__global__ __launch_bounds__(256, 2)
void qkv_kernel(const float* __restrict__ x,
                const float* __restrict__ bq,
                const float* __restrict__ bk,
                const float* __restrict__ bv,
                const short* __restrict__ wt,
                short* __restrict__ Qh, short* __restrict__ Ql,
                short* __restrict__ Kh, short* __restrict__ Kl,
                short* __restrict__ Vt) {
  __shared__ short X[16896];
  int tid = threadIdx.x;
  int r0 = blockIdx.x * 32;
  int bidx = r0 >> 13;
  int tl0 = r0 & 8191;
#pragma unroll
  for (int i = 0; i < 8; i++) {
    int E = i * 1024 + tid * 4;
    int r = E >> 8, col = E & 255;
    f32x4 v = *(const f32x4*)(x + (size_t)(r0 + r) * 256 + col);
    s16x4 h, lo;
#pragma unroll
    for (int j = 0; j < 4; j++) {
      unsigned short hh = f2bf(v[j]);
      h[j] = (short)hh;
      lo[j] = (short)f2bf(v[j] - bf2f(hh));
    }
    *(s16x4*)&X[r * 264 + col] = h;
    *(s16x4*)&X[8448 + r * 264 + col] = lo;
  }
  __syncthreads();

  int lane = tid & 63, wv = tid >> 6;
  int quad = lane >> 4, lq = lane & 15;

  {
    int strip = wv & 1;
    const short* WhT = wt + ((wv < 2) ? 0 : 131072);
    const short* WlT = WhT + 65536;
    f32x4 acc[16];
#pragma unroll
    for (int nt = 0; nt < 16; nt++) acc[nt] = (f32x4){0.f, 0.f, 0.f, 0.f};
    int arow = (strip * 16 + lq) * 264 + quad * 8;
#pragma unroll
    for (int c = 0; c < 8; c++) {
      s16x8 xh = *(const s16x8*)&X[arow + c * 32];
      s16x8 xl = *(const s16x8*)&X[8448 + arow + c * 32];
#pragma unroll
      for (int nt = 0; nt < 16; nt++) {
        int boff = (nt * 16 + lq) * 256 + c * 32 + quad * 8;
        s16x8 wh = *(const s16x8*)(WhT + boff);
        s16x8 wl = *(const s16x8*)(WlT + boff);
        acc[nt] = MFMA16(xh, wh, acc[nt]);
        acc[nt] = MFMA16(xl, wh, acc[nt]);
        acc[nt] = MFMA16(xh, wl, acc[nt]);
      }
    }
    const float* bias = (wv < 2) ? bq : bk;
    short* Oh = (wv < 2) ? Qh : Kh;
    short* Ol = (wv < 2) ? Ql : Kl;
#pragma unroll
    for (int nt = 0; nt < 16; nt++) {
      int col = nt * 16 + lq;
      float bb = bias[col];
#pragma unroll
      for (int r = 0; r < 4; r++) {
        int row = r0 + strip * 16 + quad * 4 + r;
        float val = acc[nt][r] + bb;
        unsigned short hi = f2bf(val);
        unsigned short lo = f2bf(val - bf2f(hi));
        Oh[row * 256 + col] = (short)hi;
        Ol[row * 256 + col] = (short)lo;
      }
    }
  }
  {
    const short* WhT = wt + 262144;
    const short* WlT = wt + 327680;
    f32x4 acc[4][2];
#pragma unroll
    for (int mt = 0; mt < 4; mt++)
#pragma unroll
      for (int nt = 0; nt < 2; nt++) acc[mt][nt] = (f32x4){0.f, 0.f, 0.f, 0.f};
#pragma unroll
    for (int c = 0; c < 8; c++) {
      int co = c * 32 + quad * 8;
      s16x8 xh0 = *(const s16x8*)&X[lq * 264 + co];
      s16x8 xl0 = *(const s16x8*)&X[8448 + lq * 264 + co];
      s16x8 xh1 = *(const s16x8*)&X[(16 + lq) * 264 + co];
      s16x8 xl1 = *(const s16x8*)&X[8448 + (16 + lq) * 264 + co];
#pragma unroll
      for (int mt = 0; mt < 4; mt++) {
        int aoff = (wv * 64 + mt * 16 + lq) * 256 + co;
        s16x8 wh = *(const s16x8*)(WhT + aoff);
        s16x8 wl = *(const s16x8*)(WlT + aoff);
        acc[mt][0] = MFMA16(wh, xh0, acc[mt][0]);
        acc[mt][0] = MFMA16(wl, xh0, acc[mt][0]);
        acc[mt][0] = MFMA16(wh, xl0, acc[mt][0]);
        acc[mt][1] = MFMA16(wh, xh1, acc[mt][1]);
        acc[mt][1] = MFMA16(wl, xh1, acc[mt][1]);
        acc[mt][1] = MFMA16(wh, xl1, acc[mt][1]);
      }
    }
#pragma unroll
    for (int mt = 0; mt < 4; mt++) {
#pragma unroll
      for (int r = 0; r < 4; r++) {
        int drow = wv * 64 + mt * 16 + quad * 4 + r;
        float bb = bv[drow];
#pragma unroll
        for (int nt = 0; nt < 2; nt++) {
          float val = acc[mt][nt][r] + bb;
          Vt[(bidx * 256 + drow) * 8192 + tl0 + nt * 16 + lq] = (short)f2bf(val);
        }
      }
    }
  }
}

// ---------------- kernel 3: flash attention ----------------
// 256 blocks: (b, t0 tile of 64). 8 waves: strip = wv&3 (16 q-rows),
// shalf = wv>>2 (32 of the 64 staged s-cols). S computed TRANSPOSED
// (A=K, B=Q) so softmax state (m,l,alpha) is lane-resident per q.
__global__ __launch_bounds__(512, 2)
void attn_kernel(const short* __restrict__ Qh, const short* __restrict__ Ql,
                 const short* __restrict__ Kh, const short* __restrict__ Kl,
                 const short* __restrict__ Vt,
                 float* __restrict__ out) {
  __shared__ short sm[57344];          // 114688 B
  short* KhL = sm;                     // [64][264]
  short* KlL = sm + 16896;             // [64][264]
  short* VtL = sm + 33792;             // [256][72]
  short* PLb = sm + 52224;             // 8 waves x [16][40]  (P stored [q][s])
  int tid = threadIdx.x;
  int lane = tid & 63, wv = tid >> 6, quad = lane >> 4, lq = lane & 15;
  int strip = wv & 3, shalf = wv >> 2;
  short* PL = PLb + wv * 640;
  int blk = blockIdx.x;
  int b = blk >> 7;
  int t0 = (blk & 127) * 64;
  int row0g = b * 8192 + t0;

  // Q fragments resident in registers (16 rows per wave, K=256)
  s16x8 qh[8], ql[8];
  {
    int qoff = (row0g + strip * 16 + lq) * 256 + quad * 8;
#pragma unroll
    for (int c = 0; c < 8; c++) {
      qh[c] = *(const s16x8*)(Qh + qoff + c * 32);
      ql[c] = *(const s16x8*)(Ql + qoff + c * 32);
    }
  }
  float m_ = -__builtin_inff();        // per-lane: q = strip*16 + lq
  float l_ = 0.f;
  f32x4 Oacc[16];
#pragma unroll
  for (int dt = 0; dt < 16; dt++) Oacc[dt] = (f32x4){0.f, 0.f, 0.f, 0.f};

  // prefetch tile 0 into registers (12 x b128 per thread)
  u32x4 kh_r[4], kl_r[4], vt_r[4];
#pragma unroll
  for (int i = 0; i < 4; i++) {
    int L = i * 512 + tid;
    int s = L >> 5, g = L & 31;
    int d = L >> 3, g2 = L & 7;
    kh_r[i] = *(const u32x4*)(Kh + (b * 8192 + s) * 256 + g * 8);
    kl_r[i] = *(const u32x4*)(Kl + (b * 8192 + s) * 256 + g * 8);
    vt_r[i] = *(const u32x4*)(Vt + (b * 256 + d) * 8192 + g2 * 8);
  }

  for (int it = 0; it < 128; it++) {
    // commit prefetched tile to LDS
#pragma unroll
    for (int i = 0; i < 4; i++) {
      int L = i * 512 + tid;
      int s = L >> 5, g = L & 31;
      int d = L >> 3, g2 = L & 7;
      *(u32x4*)&KhL[s * 264 + g * 8] = kh_r[i];
      *(u32x4*)&KlL[s * 264 + g * 8] = kl_r[i];
      *(u32x4*)&VtL[d * 72 + g2 * 8] = vt_r[i];
    }
    __syncthreads();
    // prefetch next tile (overlaps with compute below)
    {
      int s0n = ((it + 1) & 127) * 64;
#pragma unroll
      for (int i = 0; i < 4; i++) {
        int L = i * 512 + tid;
        int s = L >> 5, g = L & 31;
        int d = L >> 3, g2 = L & 7;
        kh_r[i] = *(const u32x4*)(Kh + (b * 8192 + s0n + s) * 256 + g * 8);
        kl_r[i] = *(const u32x4*)(Kl + (b * 8192 + s0n + s) * 256 + g * 8);
        vt_r[i] = *(const u32x4*)(Vt + (b * 256 + d) * 8192 + s0n + g2 * 8);
      }
    }
    // S^T = K Q^T over this wave's 32 s (2 row-tiles), 3-term compensated.
    // C layout: col = q = lane&15, row = s_local = quad*4 + r.
    f32x4 ahh0 = (f32x4){0.f, 0.f, 0.f, 0.f}, ahh1 = ahh0;
    f32x4 alh0 = ahh0, alh1 = ahh0, ahl0 = ahh0, ahl1 = ahh0;
    int krowA = (shalf * 32 + lq) * 264;
    int krowB = krowA + 16 * 264;
#pragma unroll
    for (int c = 0; c < 8; c++) {
      int off = c * 32 + quad * 8;
      s16x8 kh0 = *(const s16x8*)&KhL[krowA + off];
      s16x8 kh1 = *(const s16x8*)&KhL[krowB + off];
      s16x8 kl0 = *(const s16x8*)&KlL[krowA + off];
      s16x8 kl1 = *(const s16x8*)&KlL[krowB + off];
      ahh0 = MFMA16(kh0, qh[c], ahh0);
      ahh1 = MFMA16(kh1, qh[c], ahh1);
      alh0 = MFMA16(kh0, ql[c], alh0);
      alh1 = MFMA16(kh1, ql[c], alh1);
      ahl0 = MFMA16(kl0, qh[c], ahl0);
      ahl1 = MFMA16(kl1, qh[c], ahl1);
    }
    f32x4 a0, a1;
#pragma unroll
    for (int r = 0; r < 4; r++) {
      a0[r] = ahh0[r] + alh0[r] + ahl0[r];
      a1[r] = ahh1[r] + alh1[r] + ahl1[r];
    }
    // in-lane online softmax: reduce over s (regs + quad lanes)
    float mx = fmaxf(fmaxf(fmaxf(a0[0], a0[1]), fmaxf(a0[2], a0[3])),
                     fmaxf(fmaxf(a1[0], a1[1]), fmaxf(a1[2], a1[3])));
    mx = fmaxf(mx, __shfl_xor(mx, 16));
    mx = fmaxf(mx, __shfl_xor(mx, 32));
    float mn = fmaxf(m_, mx);
    float alpha = __expf(m_ - mn);
    m_ = mn;
    float p0[4], p1[4];
#pragma unroll
    for (int r = 0; r < 4; r++) {
      p0[r] = __expf(a0[r] - mn);
      p1[r] = __expf(a1[r] - mn);
    }
    float rs = (p0[0] + p0[1]) + (p0[2] + p0[3]) +
               (p1[0] + p1[1]) + (p1[2] + p1[3]);
    rs += __shfl_xor(rs, 16);
    rs += __shfl_xor(rs, 32);
    l_ = l_ * alpha + rs;
    // packed P store: P[q=lq][s_local = tile*16 + quad*4 + r]
    {
      s16x4 pk0, pk1;
#pragma unroll
      for (int r = 0; r < 4; r++) {
        pk0[r] = (short)f2bf(p0[r]);
        pk1[r] = (short)f2bf(p1[r]);
      }
      *(s16x4*)&PL[lq * 40 + quad * 4] = pk0;
      *(s16x4*)&PL[lq * 40 + 16 + quad * 4] = pk1;
    }
    // rescale O by alpha (per C-row q = quad*4+r); skip if wave-uniform no-op
    if (!__all(alpha == 1.f)) {
      float alr[4];
#pragma unroll
      for (int r = 0; r < 4; r++) alr[r] = __shfl(alpha, quad * 4 + r);
#pragma unroll
      for (int dt = 0; dt < 16; dt++) {
#pragma unroll
        for (int r = 0; r < 4; r++) Oacc[dt][r] *= alr[r];
      }
    }
    // O += P V, K=32 (A = P[q][s] from LDS, B = Vt rows)
    s16x8 pf = *(const s16x8*)&PL[lq * 40 + quad * 8];
#pragma unroll
    for (int dt = 0; dt < 16; dt++) {
      s16x8 vf = *(const s16x8*)&VtL[(dt * 16 + lq) * 72 + shalf * 32 + quad * 8];
      Oacc[dt] = MFMA16(pf, vf, Oacc[dt]);
    }
    __syncthreads();
  }

  // ---- pair merge (shalf 0 <-> 1 per strip) via LDS, 2 passes of 8 dt ----
  float* Ob = (float*)sm;              // [64][132] fp32
  float* Msh = (float*)sm + 64 * 132;  // m [2][64], l [2][64]
  float* Lsh = Msh + 128;
  float a0s[4], a1s[4], linv[4];
#pragma unroll
  for (int half = 0; half < 2; half++) {
    if (half == 0) {
      Msh[shalf * 64 + strip * 16 + lq] = m_;
      Lsh[shalf * 64 + strip * 16 + lq] = l_;
    }
    if (shalf == 1) {
#pragma unroll
      for (int dt2 = 0; dt2 < 8; dt2++) {
        int dt = half * 8 + dt2;
#pragma unroll
        for (int r = 0; r < 4; r++)
          Ob[(strip * 16 + quad * 4 + r) * 132 + dt2 * 16 + lq] = Oacc[dt][r];
      }
    }
    __syncthreads();
    if (shalf == 0) {
      if (half == 0) {
#pragma unroll
        for (int r = 0; r < 4; r++) {
          int rb = strip * 16 + quad * 4 + r;
          float m0 = Msh[rb], l0 = Lsh[rb];
          float m1 = Msh[64 + rb], l1 = Lsh[64 + rb];
          float mm = fmaxf(m0, m1);
          a0s[r] = __expf(m0 - mm);
          a1s[r] = __expf(m1 - mm);
          linv[r] = 1.f / (l0 * a0s[r] + l1 * a1s[r]);
        }
      }
#pragma unroll
      for (int dt2 = 0; dt2 < 8; dt2++) {
        int dt = half * 8 + dt2;
#pragma unroll
        for (int r = 0; r < 4; r++) {
          int rb = strip * 16 + quad * 4 + r;
          float o1 = Ob[rb * 132 + dt2 * 16 + lq];
          int row = row0g + rb;
          out[row * 256 + dt * 16 + lq] =
              (Oacc[dt][r] * a0s[r] + o1 * a1s[r]) * linv[r];
        }
      }
    }
    __syncthreads();
  }
}

// ---------------- launcher ----------------
extern "C" void kernel_launch(void* const* d_in, const int* in_sizes, int n_in,
                              void* d_out, int out_size, void* d_ws, size_t ws_size,
                              hipStream_t stream) {
  const float* x  = (const float*)d_in[0];
  const float* Wq = (const float*)d_in[1];
  const float* bq = (const float*)d_in[2];
  const float* Wk = (const float*)d_in[3];
  const float* bk = (const float*)d_in[4];
  const float* Wv = (const float*)d_in[5];
  const float* bv = (const float*)d_in[6];
  float* out = (float*)d_out;
  short* ws = (short*)d_ws;
  short* wt = ws;
  short* Qh = ws + 393216;
  short* Ql = Qh + 4194304;
  short* Kh = Ql + 4194304;
  short* Kl = Kh + 4194304;
  short* Vt = Kl + 4194304;
  hipLaunchKernelGGL(wtrans_kernel, dim3(768), dim3(256), 0, stream, Wq, Wk, Wv, wt);
  hipLaunchKernelGGL(qkv_kernel, dim3(512), dim3(256), 0, stream,
                     x, bq, bk, bv, wt, Qh, Ql, Kh, Kl, Vt);
  hipLaunchKernelGGL(attn_kernel, dim3(256), dim3(512), 0, stream,
                     Qh, Ql, Kh, Kl, Vt, out);
}

// Round 6
// 385.835 us; speedup vs baseline: 1.9289x; 1.2715x over previous
//
#include <hip/hip_runtime.h>
#include <stdint.h>

// ---- types ----
typedef __attribute__((ext_vector_type(4))) float f32x4;
typedef __attribute__((ext_vector_type(16))) float f32x16;
typedef __attribute__((ext_vector_type(8))) short s16x8;
typedef __attribute__((ext_vector_type(4))) short s16x4;
typedef __attribute__((ext_vector_type(4))) unsigned int u32x4;
typedef __attribute__((ext_vector_type(8))) _Float16 f16x8;
typedef __attribute__((ext_vector_type(4))) _Float16 f16x4;

#define MFMA16(a, b, c) __builtin_amdgcn_mfma_f32_16x16x32_bf16((a), (b), (c), 0, 0, 0)
#define MFMA32H(a, b, c) __builtin_amdgcn_mfma_f32_32x32x16_f16((a), (b), (c), 0, 0, 0)

// B=2, T=8192, D=256; rows = B*T = 16384 flat.

__device__ __forceinline__ unsigned short f2bf(float f) {
  unsigned int u = __float_as_uint(f);
  u += 0x7FFFu + ((u >> 16) & 1u);  // RNE
  return (unsigned short)(u >> 16);
}
__device__ __forceinline__ float bf2f(unsigned short h) {
  return __uint_as_float(((unsigned int)h) << 16);
}

// ---------------- kernel 1: weight transpose + hi/lo split (bf16) -----------
__global__ void wtrans_kernel(const float* __restrict__ Wq,
                              const float* __restrict__ Wk,
                              const float* __restrict__ Wv,
                              short* __restrict__ wt) {
  int idx = blockIdx.x * 256 + threadIdx.x;   // 768 blocks * 256
  int w = idx >> 16;
  int rc = idx & 65535;
  int d = rc >> 8;
  int n = rc & 255;
  const float* Ws = (w == 0) ? Wq : ((w == 1) ? Wk : Wv);
  float v = Ws[rc];
  unsigned short hi = f2bf(v);
  unsigned short lo = f2bf(v - bf2f(hi));
  short* th = wt + w * 131072;
  th[n * 256 + d] = (short)hi;
  th[65536 + n * 256 + d] = (short)lo;
}

// ---------------- kernel 2: QKV projection (3-term bf16 MFMA) ----------------
// Outputs now fp16: Qf/Kf [16384][256], Vt [2][256][8192].
__global__ __launch_bounds__(256, 2)
void qkv_kernel(const float* __restrict__ x,
                const float* __restrict__ bq,
                const float* __restrict__ bk,
                const float* __restrict__ bv,
                const short* __restrict__ wt,
                short* __restrict__ Qf, short* __restrict__ Kf,
                short* __restrict__ Vt) {
  __shared__ short X[16896];
  int tid = threadIdx.x;
  int r0 = blockIdx.x * 32;
  int bidx = r0 >> 13;
  int tl0 = r0 & 8191;
#pragma unroll
  for (int i = 0; i < 8; i++) {
    int E = i * 1024 + tid * 4;
    int r = E >> 8, col = E & 255;
    f32x4 v = *(const f32x4*)(x + (size_t)(r0 + r) * 256 + col);
    s16x4 h, lo;
#pragma unroll
    for (int j = 0; j < 4; j++) {
      unsigned short hh = f2bf(v[j]);
      h[j] = (short)hh;
      lo[j] = (short)f2bf(v[j] - bf2f(hh));
    }
    *(s16x4*)&X[r * 264 + col] = h;
    *(s16x4*)&X[8448 + r * 264 + col] = lo;
  }
  __syncthreads();

  int lane = tid & 63, wv = tid >> 6;
  int quad = lane >> 4, lq = lane & 15;

  {
    int strip = wv & 1;
    const short* WhT = wt + ((wv < 2) ? 0 : 131072);
    const short* WlT = WhT + 65536;
    f32x4 acc[16];
#pragma unroll
    for (int nt = 0; nt < 16; nt++) acc[nt] = (f32x4){0.f, 0.f, 0.f, 0.f};
    int arow = (strip * 16 + lq) * 264 + quad * 8;
#pragma unroll
    for (int c = 0; c < 8; c++) {
      s16x8 xh = *(const s16x8*)&X[arow + c * 32];
      s16x8 xl = *(const s16x8*)&X[8448 + arow + c * 32];
#pragma unroll
      for (int nt = 0; nt < 16; nt++) {
        int boff = (nt * 16 + lq) * 256 + c * 32 + quad * 8;
        s16x8 wh = *(const s16x8*)(WhT + boff);
        s16x8 wl = *(const s16x8*)(WlT + boff);
        acc[nt] = MFMA16(xh, wh, acc[nt]);
        acc[nt] = MFMA16(xl, wh, acc[nt]);
        acc[nt] = MFMA16(xh, wl, acc[nt]);
      }
    }
    const float* bias = (wv < 2) ? bq : bk;
    _Float16* Of = (_Float16*)((wv < 2) ? Qf : Kf);
#pragma unroll
    for (int nt = 0; nt < 16; nt++) {
      int col = nt * 16 + lq;
      float bb = bias[col];
#pragma unroll
      for (int r = 0; r < 4; r++) {
        int row = r0 + strip * 16 + quad * 4 + r;
        Of[row * 256 + col] = (_Float16)(acc[nt][r] + bb);
      }
    }
  }
  {
    const short* WhT = wt + 262144;
    const short* WlT = wt + 327680;
    f32x4 acc[4][2];
#pragma unroll
    for (int mt = 0; mt < 4; mt++)
#pragma unroll
      for (int nt = 0; nt < 2; nt++) acc[mt][nt] = (f32x4){0.f, 0.f, 0.f, 0.f};
#pragma unroll
    for (int c = 0; c < 8; c++) {
      int co = c * 32 + quad * 8;
      s16x8 xh0 = *(const s16x8*)&X[lq * 264 + co];
      s16x8 xl0 = *(const s16x8*)&X[8448 + lq * 264 + co];
      s16x8 xh1 = *(const s16x8*)&X[(16 + lq) * 264 + co];
      s16x8 xl1 = *(const s16x8*)&X[8448 + (16 + lq) * 264 + co];
#pragma unroll
      for (int mt = 0; mt < 4; mt++) {
        int aoff = (wv * 64 + mt * 16 + lq) * 256 + co;
        s16x8 wh = *(const s16x8*)(WhT + aoff);
        s16x8 wl = *(const s16x8*)(WlT + aoff);
        acc[mt][0] = MFMA16(wh, xh0, acc[mt][0]);
        acc[mt][0] = MFMA16(wl, xh0, acc[mt][0]);
        acc[mt][0] = MFMA16(wh, xl0, acc[mt][0]);
        acc[mt][1] = MFMA16(wh, xh1, acc[mt][1]);
        acc[mt][1] = MFMA16(wl, xh1, acc[mt][1]);
        acc[mt][1] = MFMA16(wh, xl1, acc[mt][1]);
      }
    }
#pragma unroll
    for (int mt = 0; mt < 4; mt++) {
#pragma unroll
      for (int r = 0; r < 4; r++) {
        int drow = wv * 64 + mt * 16 + quad * 4 + r;
        float bb = bv[drow];
#pragma unroll
        for (int nt = 0; nt < 2; nt++) {
          ((_Float16*)Vt)[(bidx * 256 + drow) * 8192 + tl0 + nt * 16 + lq] =
              (_Float16)(acc[mt][nt][r] + bb);
        }
      }
    }
  }
}

// ---------------- kernel 3: flash attention (fp16, q-block 128, 32x32) ------
// 256 blocks = 128 q-tiles x 2 s-blocks (each 4096 s = 64 iters of 64 s).
// 8 waves = 4 strips (32 q) x 2 shalf (32 s of the staged 64); full d=256
// per wave -> P wave-private (same-wave RAW), 2 barriers/iter.
// S^T = K Q^T (C col = q = lane&31 -> lane-resident m/l/alpha);
// O^T = V P^T. Register budget ~250; launch_bounds(512,2) enforces <=256
// (R5 lesson: (512,1) allowed >256 VGPR -> silent launch failure).
__global__ __launch_bounds__(512, 2)
void attn_kernel(const short* __restrict__ Qf, const short* __restrict__ Kf,
                 const short* __restrict__ Vt,
                 float* __restrict__ out, float* __restrict__ O1,
                 float* __restrict__ Mlg) {
  __shared__ short sm[45568];          // 91136 B
  short* KL  = sm;                     // [64][264]
  short* VtL = sm + 16896;             // [256][72]
  short* PLb = sm + 35328;             // 8 waves x [32 q][40]
  int tid = threadIdx.x;
  int lane = tid & 63, wv = tid >> 6;
  int lq32 = lane & 31, hh = lane >> 5, h8 = hh * 8;
  int strip = wv & 3, sh = wv >> 2;
  short* PL = PLb + wv * 1280;
  int blk = blockIdx.x;
  int qt = blk >> 1, sblk = blk & 1;
  int row0g = qt * 128;
  int b = row0g >> 13;
  int sbase = b * 8192 + sblk * 4096;

  // Q fragments (B-operand): q = strip*32 + lq32, k = st*16 + h8 + j
  f16x8 qf[16];
  {
    const _Float16* qrow =
        (const _Float16*)Qf + (size_t)(row0g + strip * 32 + lq32) * 256 + h8;
#pragma unroll
    for (int st = 0; st < 16; st++) qf[st] = *(const f16x8*)(qrow + st * 16);
  }
  float m_ = -__builtin_inff();        // per-lane q
  float l_ = 0.f;
  f32x16 Oacc[8];                      // O^T[d = dt*32 + row][q]
#pragma unroll
  for (int dt = 0; dt < 8; dt++)
#pragma unroll
    for (int i = 0; i < 16; i++) Oacc[dt][i] = 0.f;

  // prefetch tile 0 (K: 64x256 fp16 = 32KB; V: 256x64 fp16 = 32KB)
  u32x4 k_r[4], vt_r[4];
#pragma unroll
  for (int i = 0; i < 4; i++) {
    int L = i * 512 + tid;
    int s = L >> 5, g = L & 31;
    int d = L >> 3, g2 = L & 7;
    k_r[i] = *(const u32x4*)(Kf + (size_t)(sbase + s) * 256 + g * 8);
    vt_r[i] = *(const u32x4*)(Vt + (size_t)(b * 256 + d) * 8192 +
                              sblk * 4096 + g2 * 8);
  }

  for (int it = 0; it < 64; it++) {
    // commit staged tile to LDS
#pragma unroll
    for (int i = 0; i < 4; i++) {
      int L = i * 512 + tid;
      int s = L >> 5, g = L & 31;
      int d = L >> 3, g2 = L & 7;
      *(u32x4*)&KL[s * 264 + g * 8] = k_r[i];
      *(u32x4*)&VtL[d * 72 + g2 * 8] = vt_r[i];
    }
    __syncthreads();
    // prefetch next tile (overlaps compute)
    {
      int s0n = ((it + 1) & 63) * 64;
#pragma unroll
      for (int i = 0; i < 4; i++) {
        int L = i * 512 + tid;
        int s = L >> 5, g = L & 31;
        int d = L >> 3, g2 = L & 7;
        k_r[i] = *(const u32x4*)(Kf + (size_t)(sbase + s0n + s) * 256 + g * 8);
        vt_r[i] = *(const u32x4*)(Vt + (size_t)(b * 256 + d) * 8192 +
                                  sblk * 4096 + s0n + g2 * 8);
      }
    }
    // S^T = K Q^T over wave's 32 s x 32 q (single-term fp16)
    f32x16 sacc;
#pragma unroll
    for (int i = 0; i < 16; i++) sacc[i] = 0.f;
    int krow = (sh * 32 + lq32) * 264 + h8;
#pragma unroll
    for (int st = 0; st < 16; st++) {
      f16x8 kf = *(const f16x8*)&KL[krow + st * 16];
      sacc = MFMA32H(kf, qf[st], sacc);
    }
    // in-lane online softmax (16 regs + partner half-wave)
    float mx = sacc[0];
#pragma unroll
    for (int i = 1; i < 16; i++) mx = fmaxf(mx, sacc[i]);
    mx = fmaxf(mx, __shfl_xor(mx, 32));
    float mn = fmaxf(m_, mx);
    float alpha = __expf(m_ - mn);
    m_ = mn;
    float rs = 0.f;
#pragma unroll
    for (int i = 0; i < 16; i++) {
      sacc[i] = __expf(sacc[i] - mn);
      rs += sacc[i];
    }
    rs += __shfl_xor(rs, 32);
    l_ = l_ * alpha + rs;
    // P -> wave-private LDS [q=lq32][s]: reg 4g+j at s = 8g + 4hh + j
#pragma unroll
    for (int g = 0; g < 4; g++) {
      f16x4 pk;
#pragma unroll
      for (int j = 0; j < 4; j++) pk[j] = (_Float16)sacc[g * 4 + j];
      *(f16x4*)&PL[lq32 * 40 + 8 * g + 4 * hh] = pk;
    }
    // rescale O^T (in-lane per q); skip when wave-uniform no-op
    if (!__all(alpha == 1.f)) {
#pragma unroll
      for (int dt = 0; dt < 8; dt++) Oacc[dt] = Oacc[dt] * alpha;
    }
    // O^T += V P^T (A = V rows, B = P); same-wave RAW via lgkmcnt order
    f16x8 pf0 = *(const f16x8*)&PL[lq32 * 40 + h8];
    f16x8 pf1 = *(const f16x8*)&PL[lq32 * 40 + 16 + h8];
#pragma unroll
    for (int dt = 0; dt < 8; dt++) {
      int vrow = (dt * 32 + lq32) * 72 + sh * 32;
      f16x8 vf0 = *(const f16x8*)&VtL[vrow + h8];
      f16x8 vf1 = *(const f16x8*)&VtL[vrow + 16 + h8];
      Oacc[dt] = MFMA32H(vf0, pf0, Oacc[dt]);
      Oacc[dt] = MFMA32H(vf1, pf1, Oacc[dt]);
    }
    __syncthreads();
  }

  // ---- epilogue: shalf pair-merge + coalesced partial write ----
  float* smf = (float*)sm;             // Ob: 4 strips x [32 q][132] f32
  float* Msh = smf + 16896;            // m [2][4][32], l at +256
  if (lane < 32) {
    Msh[(sh * 4 + strip) * 32 + lq32] = m_;
    Msh[256 + (sh * 4 + strip) * 32 + lq32] = l_;
  }
  __syncthreads();
  float m1 = Msh[((1 - sh) * 4 + strip) * 32 + lq32];
  float l1 = Msh[256 + ((1 - sh) * 4 + strip) * 32 + lq32];
  float mm = fmaxf(m_, m1);
  float e0 = __expf(m_ - mm);
  float e1 = __expf(m1 - mm);
  float* Opart = (sblk == 0) ? out : O1;
  if (sh == 0 && lane < 32) {          // combined (m, l) for this s-block
    float lsum = l_ * e0 + l1 * e1;
    int rowq = row0g + strip * 32 + lq32;
    Mlg[sblk * 32768 + rowq * 2] = mm;
    Mlg[sblk * 32768 + rowq * 2 + 1] = lsum;
  }
  float* Ob = smf + strip * 4224;      // 32*132
#pragma unroll
  for (int hd = 0; hd < 2; hd++) {
    __syncthreads();
    if (sh == 1) {
#pragma unroll
      for (int dt2 = 0; dt2 < 4; dt2++) {
        int dt = hd * 4 + dt2;
#pragma unroll
        for (int g = 0; g < 4; g++) {
          f32x4 v = {Oacc[dt][g * 4], Oacc[dt][g * 4 + 1],
                     Oacc[dt][g * 4 + 2], Oacc[dt][g * 4 + 3]};
          *(f32x4*)&Ob[lq32 * 132 + dt2 * 32 + 8 * g + 4 * hh] = v;
        }
      }
    }
    __syncthreads();
    if (sh == 0) {
#pragma unroll
      for (int dt2 = 0; dt2 < 4; dt2++) {
        int dt = hd * 4 + dt2;
#pragma unroll
        for (int g = 0; g < 4; g++) {
          float* ad = &Ob[lq32 * 132 + dt2 * 32 + 8 * g + 4 * hh];
          f32x4 o1 = *(f32x4*)ad;
          f32x4 cmb;
#pragma unroll
          for (int j = 0; j < 4; j++)
            cmb[j] = Oacc[dt][g * 4 + j] * e0 + o1[j] * e1;
          *(f32x4*)ad = cmb;
        }
      }
    }
    __syncthreads();
    // cooperative coalesced write of this d-half: 128 q x 32 f32x4 groups
#pragma unroll
    for (int i = 0; i < 8; i++) {
      int idx = i * 512 + tid;
      int q = idx >> 5, gb = idx & 31;
      f32x4 v = *(f32x4*)&smf[(q >> 5) * 4224 + (q & 31) * 132 + gb * 4];
      *(f32x4*)&Opart[(size_t)(row0g + q) * 256 + hd * 128 + gb * 4] = v;
    }
  }
}

// ---------------- kernel 4: s-split merge ----------------
__global__ void merge_kernel(const float* __restrict__ O1,
                             const float* __restrict__ Mlg,
                             float* __restrict__ out) {
  int idx = blockIdx.x * 256 + threadIdx.x;   // 4096 blocks
  int q = idx >> 6, dg = idx & 63;
  float m0 = Mlg[q * 2], l0 = Mlg[q * 2 + 1];
  float m1 = Mlg[32768 + q * 2], l1 = Mlg[32768 + q * 2 + 1];
  float mm = fmaxf(m0, m1);
  float e0 = __expf(m0 - mm), e1 = __expf(m1 - mm);
  float inv = 1.f / (l0 * e0 + l1 * e1);
  f32x4 a = *(const f32x4*)(out + (size_t)q * 256 + dg * 4);
  f32x4 bb = *(const f32x4*)(O1 + (size_t)q * 256 + dg * 4);
  f32x4 r;
#pragma unroll
  for (int j = 0; j < 4; j++) r[j] = (a[j] * e0 + bb[j] * e1) * inv;
  *(f32x4*)(out + (size_t)q * 256 + dg * 4) = r;
}

// ---------------- launcher ----------------
extern "C" void kernel_launch(void* const* d_in, const int* in_sizes, int n_in,
                              void* d_out, int out_size, void* d_ws, size_t ws_size,
                              hipStream_t stream) {
  const float* x  = (const float*)d_in[0];
  const float* Wq = (const float*)d_in[1];
  const float* bq = (const float*)d_in[2];
  const float* Wk = (const float*)d_in[3];
  const float* bk = (const float*)d_in[4];
  const float* Wv = (const float*)d_in[5];
  const float* bv = (const float*)d_in[6];
  float* out = (float*)d_out;
  short* ws = (short*)d_ws;
  // ws layout (shorts): wt 393216 | Qf 4194304 | Kf 4194304 | Vt 4194304 |
  // O1 (float 4194304) at short-offset 12976128. Mlg aliases wt (dead after
  // qkv). Total = 42,729,472 B (same as the validated R4 footprint).
  short* wt = ws;
  short* Qf = ws + 393216;
  short* Kf = Qf + 4194304;
  short* Vt = Kf + 4194304;
  float* O1  = (float*)(ws + 12976128);
  float* Mlg = (float*)ws;
  hipLaunchKernelGGL(wtrans_kernel, dim3(768), dim3(256), 0, stream, Wq, Wk, Wv, wt);
  hipLaunchKernelGGL(qkv_kernel, dim3(512), dim3(256), 0, stream,
                     x, bq, bk, bv, wt, Qf, Kf, Vt);
  hipLaunchKernelGGL(attn_kernel, dim3(256), dim3(512), 0, stream,
                     Qf, Kf, Vt, out, O1, Mlg);
  hipLaunchKernelGGL(merge_kernel, dim3(4096), dim3(256), 0, stream,
                     O1, Mlg, out);
}